// Round 16
// baseline (168.864 us; speedup 1.0000x reference)
//
#include <hip/hip_runtime.h>

typedef __attribute__((ext_vector_type(4))) float f32x4;
typedef __attribute__((ext_vector_type(8))) __bf16 bf16x8;
typedef __attribute__((ext_vector_type(4))) unsigned short us4;
typedef __attribute__((ext_vector_type(8))) unsigned short us8;

#define B_  16
#define C_  512
#define N_  1024
#define G_  32
#define GS  16

__device__ inline unsigned short f2bf(float f) {
  unsigned u = __builtin_bit_cast(unsigned, f);
  u += 0x7fffu + ((u >> 16) & 1u);
  return (unsigned short)(u >> 16);
}

#define GLOAD_LDS16(gp, lp) __builtin_amdgcn_global_load_lds( \
    (const __attribute__((address_space(1))) unsigned int*)(gp), \
    (__attribute__((address_space(3))) unsigned int*)(lp), 16, 0, 0)

// ---------------- fused GroupNorm: stats + normalize + transpose, one x read ----------------
__global__ __launch_bounds__(256) void gn_fused(const float* __restrict__ x,
                                                const float* __restrict__ gamma,
                                                const float* __restrict__ beta,
                                                unsigned short* __restrict__ ht) {
  int bg = blockIdx.x;            // 0..511
  int b = bg >> 5, g = bg & 31;
  int tid = threadIdx.x;
  __shared__ float Lx[16][1028];
  __shared__ float r1[256], r2[256];
  const float* xp = x + ((long)b * C_ + g * 16) * N_;
  float s = 0.f, ss = 0.f;
#pragma unroll
  for (int i = 0; i < 16; ++i) {
    f32x4 v = *(const f32x4*)&xp[(long)i * N_ + tid * 4];
    s  += v.x + v.y + v.z + v.w;
    ss += v.x * v.x + v.y * v.y + v.z * v.z + v.w * v.w;
    *(f32x4*)&Lx[i][tid * 4] = v;
  }
  r1[tid] = s; r2[tid] = ss; __syncthreads();
  for (int off = 128; off > 0; off >>= 1) {
    if (tid < off) { r1[tid] += r1[tid + off]; r2[tid] += r2[tid + off]; }
    __syncthreads();
  }
  float mean = r1[0] * (1.f / 16384.f);
  float var  = r2[0] * (1.f / 16384.f) - mean * mean;
  float rstd = rsqrtf(var + 1e-6f);
  float gm[8], bt[8];
  int cbase = g * 16 + (tid & 1) * 8;
#pragma unroll
  for (int k = 0; k < 8; ++k) {
    gm[k] = gamma[cbase + k] * rstd;
    bt[k] = beta[cbase + k] - mean * gm[k];
  }
#pragma unroll
  for (int j = 0; j < 8; ++j) {
    int lin = tid + j * 256;
    int n = lin >> 1;
    int c8 = (lin & 1) * 8;
    us8 o;
#pragma unroll
    for (int k = 0; k < 8; ++k)
      o[k] = f2bf(Lx[c8 + k][n] * gm[k] + bt[k]);
    *(us8*)&ht[((long)b * N_ + n) * C_ + g * 16 + c8] = o;
  }
}

// ---------------- weight conversion + bvo = wo . bv ----------------
__global__ __launch_bounds__(256) void convert_w(const float* __restrict__ wq, const float* __restrict__ wk,
                                                 const float* __restrict__ wo,
                                                 const float* __restrict__ bq, const float* __restrict__ bk,
                                                 const float* __restrict__ bv,
                                                 unsigned short* __restrict__ wqk,
                                                 unsigned short* __restrict__ wob, float* __restrict__ bqk,
                                                 float* __restrict__ bvo) {
  long bid = blockIdx.x;
  int tid = threadIdx.x;
  long i = bid * 256 + tid;
  if (i < C_ * C_) {
    wqk[i]           = f2bf(wq[i]);
    wqk[C_ * C_ + i] = f2bf(wk[i]);
    wob[i]           = f2bf(wo[i]);
  }
  if (i < C_) { bqk[i] = bq[i]; bqk[C_ + i] = bk[i]; }
  if (bid >= 1024) {
    int o = (int)(bid - 1024) * 256 + tid;   // 0..511
    const float* wr = wo + (long)o * 512;
    float acc = 0.f;
    for (int c = 0; c < 512; c += 4) {
      f32x4 w4 = *(const f32x4*)&wr[c];
      f32x4 b4 = *(const f32x4*)&bv[c];
      acc += w4.x * b4.x + w4.y * b4.y + w4.z * b4.z + w4.w * b4.w;
    }
    bvo[o] = acc;
  }
}

// ---------------- wvT[k,c] = wv[c,k]  (64x64 f32 LDS tiles, bf16 out) ----------------
__global__ __launch_bounds__(256) void transpose_wv(const float* __restrict__ wv,
                                                    unsigned short* __restrict__ wvT) {
  int c0 = blockIdx.x * 64, k0 = blockIdx.y * 64;
  int tid = threadIdx.x;
  __shared__ float Lt[64][65];
#pragma unroll
  for (int i = 0; i < 4; ++i) {
    int lin = tid + i * 256;
    int rr = lin >> 4;
    int q4 = (lin & 15) * 4;
    f32x4 v = *(const f32x4*)&wv[(long)(c0 + rr) * 512 + k0 + q4];
    Lt[q4 + 0][rr] = v.x; Lt[q4 + 1][rr] = v.y;
    Lt[q4 + 2][rr] = v.z; Lt[q4 + 3][rr] = v.w;
  }
  __syncthreads();
#pragma unroll
  for (int i = 0; i < 2; ++i) {
    int lin = tid + i * 256;
    int kk = lin >> 3;
    int cc = (lin & 7) * 8;
    us8 o;
#pragma unroll
    for (int j = 0; j < 8; ++j) o[j] = f2bf(Lt[kk][cc + j]);
    *(us8*)&wvT[(long)(k0 + kk) * 512 + c0 + cc] = o;
  }
}

// ---------------- WVO[o,k] = sum_c wob[o,c] * wvT[k,c]  (no LDS, L2-resident) ----------------
__device__ inline f32x4 mfma16(bf16x8 a, bf16x8 b, f32x4 c) {
  return __builtin_amdgcn_mfma_f32_16x16x32_bf16(a, b, c, 0, 0, 0);
}

__global__ __launch_bounds__(256) void wprod(const unsigned short* __restrict__ wob,
                                             const unsigned short* __restrict__ wvT,
                                             unsigned short* __restrict__ WVO) {
  int row0 = blockIdx.x * 64, col0 = blockIdx.y * 64;
  int tid = threadIdx.x, lane = tid & 63, w = tid >> 6;
  int lr = lane & 15, kh = (lane >> 4) * 8;
  f32x4 acc4[4];
#pragma unroll
  for (int n = 0; n < 4; ++n) acc4[n] = f32x4{0.f, 0.f, 0.f, 0.f};
  for (int k0 = 0; k0 < 512; k0 += 32) {
    bf16x8 af = *(const bf16x8*)&wob[(long)(row0 + w * 16 + lr) * 512 + k0 + kh];
#pragma unroll
    for (int n = 0; n < 4; ++n) {
      bf16x8 bf8 = *(const bf16x8*)&wvT[(long)(col0 + n * 16 + lr) * 512 + k0 + kh];
      acc4[n] = mfma16(af, bf8, acc4[n]);
    }
  }
  int rb = (lane >> 4) * 4;
#pragma unroll
  for (int n = 0; n < 4; ++n)
#pragma unroll
    for (int r = 0; r < 4; ++r)
      WVO[(long)(row0 + w * 16 + rb + r) * 512 + col0 + n * 16 + lr] = f2bf(acc4[n][r]);
}

// ---------------- 128x128 4-wave MFMA GEMM, 2 col-tiles/block, continuous pipeline ----------------
__device__ inline int swz(int b) { return b ^ (((b >> 9) & 1) << 5); }

// EPI: 0 = +bias[col], bf16    1 = +bias[row], bf16
//      5 = exp2(v*scale) bf16 + per-row partial sums -> rs
//      7 = v*dinv(row) + bias[col] + residual, f32x4 transposed store out[z, col, row]
// Each block computes tiles (bx, by*2) and (bx, by*2+1): one flat 2*NT-iteration pipeline.
// XSWZ: bijective XCD remap; grid = (1<<SHX, 1<<SHY, 16)
template<int EPI, int SHX, int SHY, int XSWZ>
__global__ __launch_bounds__(256, 2) void gemm128t(
    const unsigned short* __restrict__ A, long lda, long Az,
    const unsigned short* __restrict__ Bm, long ldb, long Bz,
    void* __restrict__ Dp, long ldd, long Dz,
    const float* __restrict__ bias, float scale, int K,
    const float* __restrict__ residual, float* __restrict__ rs) {
  int bx = blockIdx.x, by = blockIdx.y, bz = blockIdx.z;
  if constexpr (XSWZ) {
    int lin = bx + ((by + (bz << SHY)) << SHX);
    int cpx = 1 << (SHX + SHY + 4 - 3);        // n/8
    int l2  = (lin & 7) * cpx + (lin >> 3);
    bx = l2 & ((1 << SHX) - 1);
    by = (l2 >> SHX) & ((1 << SHY) - 1);
    bz = l2 >> (SHX + SHY);
  }
  const int z = bz;
  const long row0 = (long)bx * 128;
  const int tid  = threadIdx.x;
  const int lane = tid & 63;
  const int wave = tid >> 6;             // 0..3
  const int wm = wave >> 1;              // 0..1
  const int wn = wave & 1;               // 0..1
  const int lr = lane & 15;
  const int khb = (lane >> 4) * 16;

  __shared__ unsigned short Abuf[2][8192];   // [128][64] per buf
  __shared__ unsigned short Bbuf[2][8192];
  __shared__ float sred[128];

  const unsigned short* Ab = A  + (long)z * Az;
  const unsigned short* Bb = Bm + (long)z * Bz;

  if constexpr (EPI == 7) {
    if (tid < 128) {
      const float* rp = rs + ((long)z * 1024 + row0 + tid) * 16;
      float s = 0.f;
#pragma unroll
      for (int i = 0; i < 16; ++i) s += rp[i];
      sred[tid] = 1.f / s;
    }
    asm volatile("s_waitcnt lgkmcnt(0)" ::: "memory");
  }

  // staging source pointers (inverse-swizzled; swz is an involution, reads reuse it)
  const unsigned short* gA[4];
  const unsigned short* gB[2][4];
#pragma unroll
  for (int r = 0; r < 4; ++r) {
    int L = swz(r * 4096 + tid * 16);
    gA[r] = Ab + (row0 + (L >> 7)) * lda + ((L & 127) >> 1);
#pragma unroll
    for (int tt = 0; tt < 2; ++tt)
      gB[tt][r] = Bb + ((long)(by * 2 + tt) * 128 + (L >> 7)) * ldb + ((L & 127) >> 1);
  }

  f32x4 acc[4][4];
#pragma unroll
  for (int m = 0; m < 4; ++m)
#pragma unroll
    for (int n = 0; n < 4; ++n) acc[m][n] = f32x4{0.f, 0.f, 0.f, 0.f};

  const int NT  = K >> 6;        // 8 (K=512) or 16 (K=1024)
  const int TOT = NT * 2;
  const int ldsO = wave * 512;   // shorts within a 4KB unit
  const int rb = (lane >> 4) * 4;

  // prologue: stage tile 0 chunk 0 into buf 0
#pragma unroll
  for (int r = 0; r < 4; ++r) {
    GLOAD_LDS16(gA[r], &Abuf[0][r * 2048 + ldsO]);
    GLOAD_LDS16(gB[0][r], &Bbuf[0][r * 2048 + ldsO]);
  }

  for (int it = 0; it < TOT; ++it) {
    int s = it + 1; if (s == TOT) s = 0;           // wrap keeps vmcnt math uniform
    const int tn = (s >= NT) ? 1 : 0;
    const long ko = (long)(s - tn * NT) << 6;
    const int nb = (it + 1) & 1;
#pragma unroll
    for (int r = 0; r < 4; ++r) {
      GLOAD_LDS16(gA[r] + ko, &Abuf[nb][r * 2048 + ldsO]);
      GLOAD_LDS16(gB[tn][r] + ko, &Bbuf[nb][r * 2048 + ldsO]);
    }
    // counted wait: current chunk's 8 (oldest) landed; next chunk's 8 stay in flight
    asm volatile("s_waitcnt vmcnt(8)" ::: "memory");
    __builtin_amdgcn_s_barrier();
    __builtin_amdgcn_sched_barrier(0);
    const unsigned short* Al = Abuf[it & 1];
    const unsigned short* Bl = Bbuf[it & 1];
#pragma unroll
    for (int kk = 0; kk < 2; ++kk) {
      bf16x8 af[4], bfr[4];
#pragma unroll
      for (int m = 0; m < 4; ++m) {
        int Pb = swz((wm * 64 + m * 16 + lr) * 128 + kk * 64 + khb);
        af[m] = *(const bf16x8*)((const char*)Al + Pb);
      }
#pragma unroll
      for (int n = 0; n < 4; ++n) {
        int Pb = swz((wn * 64 + n * 16 + lr) * 128 + kk * 64 + khb);
        bfr[n] = *(const bf16x8*)((const char*)Bl + Pb);
      }
      __builtin_amdgcn_s_setprio(1);
#pragma unroll
      for (int m = 0; m < 4; ++m)
#pragma unroll
        for (int n = 0; n < 4; ++n)
          acc[m][n] = mfma16(af[m], bfr[n], acc[m][n]);
      __builtin_amdgcn_s_setprio(0);
    }
    __builtin_amdgcn_sched_barrier(0);

    // ---- tile-boundary epilogue: direct stores, overlaps next tile's in-flight loads
    if ((it & (NT - 1)) == NT - 1) {
      const int tt = (it >= NT) ? 1 : 0;
      const long col0 = (long)(by * 2 + tt) * 128;
      if constexpr (EPI == 7) {
#pragma unroll
        for (int m = 0; m < 4; ++m) {
          int lrow = wm * 64 + m * 16 + rb;
          long gr0 = row0 + lrow;
#pragma unroll
          for (int n = 0; n < 4; ++n) {
            long gc = col0 + wn * 64 + n * 16 + lr;
            long o = (long)z * (512L * 1024L) + gc * 1024L + gr0;
            f32x4 res = *(const f32x4*)&residual[o];
            float bb = bias[gc];
            f32x4 st;
#pragma unroll
            for (int r = 0; r < 4; ++r)
              st[r] = acc[m][n][r] * sred[lrow + r] + bb + res[r];
            *(f32x4*)&((float*)Dp)[o] = st;
          }
        }
      } else {
        unsigned short* Dst = (unsigned short*)Dp + (long)z * Dz;
        const int jt = by * 2 + tt;
#pragma unroll
        for (int m = 0; m < 4; ++m) {
          float ps[4] = {0.f, 0.f, 0.f, 0.f};
#pragma unroll
          for (int n = 0; n < 4; ++n) {
            float bcol = 0.f;
            if constexpr (EPI == 0) bcol = bias[col0 + wn * 64 + n * 16 + lr];
#pragma unroll
            for (int r = 0; r < 4; ++r) {
              long gr = row0 + wm * 64 + m * 16 + rb + r;
              long gc = col0 + wn * 64 + n * 16 + lr;
              float v = acc[m][n][r];
              if constexpr (EPI == 0) v += bcol;
              else if constexpr (EPI == 1) v += bias[gr];
              else if constexpr (EPI == 5) { v = exp2f(v * scale); ps[r] += v; }
              Dst[gr * ldd + gc] = f2bf(v);
            }
          }
          if constexpr (EPI == 5) {
#pragma unroll
            for (int r = 0; r < 4; ++r) {
              ps[r] += __shfl_xor(ps[r], 1);
              ps[r] += __shfl_xor(ps[r], 2);
              ps[r] += __shfl_xor(ps[r], 4);
              ps[r] += __shfl_xor(ps[r], 8);
            }
            if (lr == 0) {
#pragma unroll
              for (int r = 0; r < 4; ++r)
                rs[((long)z * 1024 + row0 + wm * 64 + m * 16 + rb + r) * 16 + jt * 2 + wn] = ps[r];
            }
          }
        }
      }
#pragma unroll
      for (int m = 0; m < 4; ++m)
#pragma unroll
        for (int n = 0; n < 4; ++n) acc[m][n] = f32x4{0.f, 0.f, 0.f, 0.f};
    }

    __builtin_amdgcn_s_barrier();
    __builtin_amdgcn_sched_barrier(0);
  }
  asm volatile("s_waitcnt vmcnt(0)" ::: "memory");   // drain wrapped stage
}

extern "C" void kernel_launch(void* const* d_in, const int* in_sizes, int n_in,
                              void* d_out, int out_size, void* d_ws, size_t ws_size,
                              hipStream_t stream) {
  const float* x     = (const float*)d_in[0];
  const float* gamma = (const float*)d_in[1];
  const float* beta  = (const float*)d_in[2];
  const float* wq    = (const float*)d_in[3];
  const float* bq    = (const float*)d_in[4];
  const float* wk    = (const float*)d_in[5];
  const float* bk    = (const float*)d_in[6];
  const float* wv    = (const float*)d_in[7];
  const float* bv    = (const float*)d_in[8];
  const float* wo    = (const float*)d_in[9];
  const float* bo    = (const float*)d_in[10];
  float* out = (float*)d_out;

  char* ws = (char*)d_ws;
  unsigned short* ht   = (unsigned short*)(ws + 0);           // [16384,512] bf16
  unsigned short* qkt  = (unsigned short*)(ws + 16777216);    // [16384,1024] bf16 (q | k)
  unsigned short* VWT  = (unsigned short*)(ws + 50331648);    // [512,16384] bf16 (wo.v)
  unsigned short* S    = (unsigned short*)(ws + 83886080);    // [16,1024,1024] bf16 (P unnorm)
  unsigned short* wqkb = (unsigned short*)(ws + 117440512);   // [1024,512] bf16
  unsigned short* wvT  = (unsigned short*)(ws + 119537664);   // [512,512] bf16 (k,c)
  unsigned short* wob  = (unsigned short*)(ws + 120061952);   // [512,512] bf16
  unsigned short* WVO  = (unsigned short*)(ws + 120586240);   // [512,512] bf16
  float* bqk           = (float*)(ws + 121110528);            // [1024] f32
  float* bvo           = (float*)(ws + 121114624);            // [512] f32
  float* rs            = (float*)(ws + 121122816);            // [16,1024,16] f32 partial rowsums

  convert_w<<<1026, 256, 0, stream>>>(wq, wk, wo, bq, bk, bv,
                                      wqkb, wob, bqk, bvo);
  transpose_wv<<<dim3(8, 8), 256, 0, stream>>>(wv, wvT);
  wprod<<<dim3(8, 8), 256, 0, stream>>>(wob, wvT, WVO);
  gn_fused<<<512, 256, 0, stream>>>(x, gamma, beta, ht);

  // G1: qkt[i, j] = sum_c ht[i,c] * wqk[j,c] + bqk[j]      (128x4 = 512 blocks, 2 tiles each)
  gemm128t<0, 0, 0, 0><<<dim3(128, 4, 1), 256, 0, stream>>>(ht, 512, 0, wqkb, 512, 0,
                                                            qkt, 1024, 0, bqk, 0.f, 512, nullptr, nullptr);
  // G2: VWT[o, t] = sum_k WVO[o,k] * ht[t,k] + bvo[o]      (4x64 = 256 blocks, 2 tiles each)
  gemm128t<1, 0, 0, 0><<<dim3(4, 64, 1), 256, 0, stream>>>(WVO, 512, 0, ht, 512, 0,
                                                           VWT, 16384, 0, bvo, 0.f, 512, nullptr, nullptr);
  // G3: P[b,i,j] = exp2(scale' * q.k), rowsum partials -> rs  (8x4x16, XCD-swz, 2 tiles each)
  gemm128t<5, 3, 2, 1><<<dim3(8, 4, 16), 256, 0, stream>>>(qkt, 1024, 1048576L, qkt + 512, 1024, 1048576L,
                                                           S, 1024, 1048576L, nullptr,
                                                           0.06375871416f, 512, nullptr, rs);
  // G4: out[b,o,n] = dinv_n * P.VWT^T + bo[o] + x[b,o,n]      (8x2x16, XCD-swz, 2 tiles each)
  gemm128t<7, 3, 1, 1><<<dim3(8, 2, 16), 256, 0, stream>>>(S, 1024, 1048576L,
                                                           VWT, 16384, 1024,
                                                           out, 0, 0, bo, 0.f, 1024, x, rs);
}

// Round 17
// 145.391 us; speedup vs baseline: 1.1614x; 1.1614x over previous
//
#include <hip/hip_runtime.h>

typedef __attribute__((ext_vector_type(4))) float f32x4;
typedef __attribute__((ext_vector_type(8))) __bf16 bf16x8;
typedef __attribute__((ext_vector_type(4))) unsigned short us4;
typedef __attribute__((ext_vector_type(8))) unsigned short us8;

#define B_  16
#define C_  512
#define N_  1024
#define G_  32
#define GS  16

__device__ inline unsigned short f2bf(float f) {
  unsigned u = __builtin_bit_cast(unsigned, f);
  u += 0x7fffu + ((u >> 16) & 1u);
  return (unsigned short)(u >> 16);
}

#define GLOAD_LDS16(gp, lp) __builtin_amdgcn_global_load_lds( \
    (const __attribute__((address_space(1))) unsigned int*)(gp), \
    (__attribute__((address_space(3))) unsigned int*)(lp), 16, 0, 0)

// ---------------- fused GroupNorm: stats + normalize + transpose, one x read ----------------
__global__ __launch_bounds__(256) void gn_fused(const float* __restrict__ x,
                                                const float* __restrict__ gamma,
                                                const float* __restrict__ beta,
                                                unsigned short* __restrict__ ht) {
  int bg = blockIdx.x;            // 0..511
  int b = bg >> 5, g = bg & 31;
  int tid = threadIdx.x;
  __shared__ float Lx[16][1028];
  __shared__ float r1[256], r2[256];
  const float* xp = x + ((long)b * C_ + g * 16) * N_;
  float s = 0.f, ss = 0.f;
#pragma unroll
  for (int i = 0; i < 16; ++i) {
    f32x4 v = *(const f32x4*)&xp[(long)i * N_ + tid * 4];
    s  += v.x + v.y + v.z + v.w;
    ss += v.x * v.x + v.y * v.y + v.z * v.z + v.w * v.w;
    *(f32x4*)&Lx[i][tid * 4] = v;
  }
  r1[tid] = s; r2[tid] = ss; __syncthreads();
  for (int off = 128; off > 0; off >>= 1) {
    if (tid < off) { r1[tid] += r1[tid + off]; r2[tid] += r2[tid + off]; }
    __syncthreads();
  }
  float mean = r1[0] * (1.f / 16384.f);
  float var  = r2[0] * (1.f / 16384.f) - mean * mean;
  float rstd = rsqrtf(var + 1e-6f);
  float gm[8], bt[8];
  int cbase = g * 16 + (tid & 1) * 8;
#pragma unroll
  for (int k = 0; k < 8; ++k) {
    gm[k] = gamma[cbase + k] * rstd;
    bt[k] = beta[cbase + k] - mean * gm[k];
  }
#pragma unroll
  for (int j = 0; j < 8; ++j) {
    int lin = tid + j * 256;
    int n = lin >> 1;
    int c8 = (lin & 1) * 8;
    us8 o;
#pragma unroll
    for (int k = 0; k < 8; ++k)
      o[k] = f2bf(Lx[c8 + k][n] * gm[k] + bt[k]);
    *(us8*)&ht[((long)b * N_ + n) * C_ + g * 16 + c8] = o;
  }
}

// ---------------- merged prep: wqk/wob conversion + bvo + wv transpose ----------------
// blocks 0..1023: convert wq/wk/wo slices; 1024..1025: bvo; 1026..1089: wvT 64x64 tiles
__global__ __launch_bounds__(256) void prep_w(const float* __restrict__ wq, const float* __restrict__ wk,
                                              const float* __restrict__ wo, const float* __restrict__ wv,
                                              const float* __restrict__ bq, const float* __restrict__ bk,
                                              const float* __restrict__ bv,
                                              unsigned short* __restrict__ wqk,
                                              unsigned short* __restrict__ wob,
                                              unsigned short* __restrict__ wvT,
                                              float* __restrict__ bqk, float* __restrict__ bvo) {
  long bid = blockIdx.x;
  int tid = threadIdx.x;
  if (bid < 1024) {
    long i = bid * 256 + tid;
    wqk[i]           = f2bf(wq[i]);
    wqk[C_ * C_ + i] = f2bf(wk[i]);
    wob[i]           = f2bf(wo[i]);
    if (i < C_) { bqk[i] = bq[i]; bqk[C_ + i] = bk[i]; }
    return;
  }
  if (bid < 1026) {
    int o = (int)(bid - 1024) * 256 + tid;   // 0..511
    const float* wr = wo + (long)o * 512;
    float acc = 0.f;
    for (int c = 0; c < 512; c += 4) {
      f32x4 w4 = *(const f32x4*)&wr[c];
      f32x4 b4 = *(const f32x4*)&bv[c];
      acc += w4.x * b4.x + w4.y * b4.y + w4.z * b4.z + w4.w * b4.w;
    }
    bvo[o] = acc;
    return;
  }
  // wv transpose tiles: t = bid-1026 in 0..63 -> (c0, k0)
  int t = (int)(bid - 1026);
  int c0 = (t & 7) * 64, k0 = (t >> 3) * 64;
  __shared__ float Lt[64][65];
#pragma unroll
  for (int i = 0; i < 4; ++i) {
    int lin = tid + i * 256;
    int rr = lin >> 4;
    int q4 = (lin & 15) * 4;
    f32x4 v = *(const f32x4*)&wv[(long)(c0 + rr) * 512 + k0 + q4];
    Lt[q4 + 0][rr] = v.x; Lt[q4 + 1][rr] = v.y;
    Lt[q4 + 2][rr] = v.z; Lt[q4 + 3][rr] = v.w;
  }
  __syncthreads();
#pragma unroll
  for (int i = 0; i < 2; ++i) {
    int lin = tid + i * 256;
    int kk = lin >> 3;
    int cc = (lin & 7) * 8;
    us8 o;
#pragma unroll
    for (int j = 0; j < 8; ++j) o[j] = f2bf(Lt[kk][cc + j]);
    *(us8*)&wvT[(long)(k0 + kk) * 512 + c0 + cc] = o;
  }
}

// ---------------- WVO[o,k] = sum_c wob[o,c] * wvT[k,c]  (no LDS, L2-resident) ----------------
__device__ inline f32x4 mfma16(bf16x8 a, bf16x8 b, f32x4 c) {
  return __builtin_amdgcn_mfma_f32_16x16x32_bf16(a, b, c, 0, 0, 0);
}

__global__ __launch_bounds__(256) void wprod(const unsigned short* __restrict__ wob,
                                             const unsigned short* __restrict__ wvT,
                                             unsigned short* __restrict__ WVO) {
  int row0 = blockIdx.x * 64, col0 = blockIdx.y * 64;
  int tid = threadIdx.x, lane = tid & 63, w = tid >> 6;
  int lr = lane & 15, kh = (lane >> 4) * 8;
  f32x4 acc4[4];
#pragma unroll
  for (int n = 0; n < 4; ++n) acc4[n] = f32x4{0.f, 0.f, 0.f, 0.f};
  for (int k0 = 0; k0 < 512; k0 += 32) {
    bf16x8 af = *(const bf16x8*)&wob[(long)(row0 + w * 16 + lr) * 512 + k0 + kh];
#pragma unroll
    for (int n = 0; n < 4; ++n) {
      bf16x8 bf8 = *(const bf16x8*)&wvT[(long)(col0 + n * 16 + lr) * 512 + k0 + kh];
      acc4[n] = mfma16(af, bf8, acc4[n]);
    }
  }
  int rb = (lane >> 4) * 4;
#pragma unroll
  for (int n = 0; n < 4; ++n)
#pragma unroll
    for (int r = 0; r < 4; ++r)
      WVO[(long)(row0 + w * 16 + rb + r) * 512 + col0 + n * 16 + lr] = f2bf(acc4[n][r]);
}

// ---------------- 128x128 4-wave MFMA GEMM, 2-phase counted-vmcnt, 2 blocks/CU ----------------
__device__ inline int swz(int b) { return b ^ (((b >> 9) & 1) << 5); }

// EPI: 0 = +bias[col], bf16    1 = +bias[row], bf16
//      5 = exp2(v*scale) bf16 + per-row partial sums -> rs
//      7 = v*dinv(row) + bias[col] + residual, f32x4 transposed store out[z, col, row]
// XSWZ: bijective XCD remap; grid = (1<<SHX, 1<<SHY, 16)
template<int EPI, int SHX, int SHY, int XSWZ>
__global__ __launch_bounds__(256, 2) void gemm128(
    const unsigned short* __restrict__ A, long lda, long Az,
    const unsigned short* __restrict__ Bm, long ldb, long Bz,
    void* __restrict__ Dp, long ldd, long Dz,
    const float* __restrict__ bias, float scale, int K,
    const float* __restrict__ residual, float* __restrict__ rs) {
  int bx = blockIdx.x, by = blockIdx.y, bz = blockIdx.z;
  if constexpr (XSWZ) {
    int lin = bx + ((by + (bz << SHY)) << SHX);
    int cpx = 1 << (SHX + SHY + 4 - 3);        // n/8
    int l2  = (lin & 7) * cpx + (lin >> 3);
    bx = l2 & ((1 << SHX) - 1);
    by = (l2 >> SHX) & ((1 << SHY) - 1);
    bz = l2 >> (SHX + SHY);
  }
  const int z = bz;
  const long row0 = (long)bx * 128;
  const long col0 = (long)by * 128;
  const int tid  = threadIdx.x;
  const int lane = tid & 63;
  const int wave = tid >> 6;             // 0..3
  const int wm = wave >> 1;              // 0..1
  const int wn = wave & 1;               // 0..1
  const int lr = lane & 15;
  const int khb = (lane >> 4) * 16;

  __shared__ unsigned short Abuf[2][8192];   // [128][64] per buf
  __shared__ unsigned short Bbuf[2][8192];
  __shared__ float sred[128];

  const unsigned short* Ab = A  + (long)z * Az;
  const unsigned short* Bb = Bm + (long)z * Bz;

  if constexpr (EPI == 7) {
    if (tid < 128) {
      const float* rp = rs + ((long)z * 1024 + row0 + tid) * 16;
      float s = 0.f;
#pragma unroll
      for (int i = 0; i < 16; ++i) s += rp[i];
      sred[tid] = 1.f / s;
    }
    asm volatile("s_waitcnt lgkmcnt(0)" ::: "memory");
  }

  // staging source pointers (inverse-swizzled; swz is an involution, reads reuse it)
  const unsigned short* gA[4];
  const unsigned short* gB[4];
#pragma unroll
  for (int r = 0; r < 4; ++r) {
    int L = swz(r * 4096 + tid * 16);
    gA[r] = Ab + (row0 + (L >> 7)) * lda + ((L & 127) >> 1);
    gB[r] = Bb + (col0 + (L >> 7)) * ldb + ((L & 127) >> 1);
  }

  f32x4 acc[4][4];
#pragma unroll
  for (int m = 0; m < 4; ++m)
#pragma unroll
    for (int n = 0; n < 4; ++n) acc[m][n] = f32x4{0.f, 0.f, 0.f, 0.f};

  const int NT = K >> 6;   // 8 or 16
  const int ldsO = wave * 512;   // shorts within a 4KB unit

  // prologue: stage tile 0 into buf 0  (8 loads)
#pragma unroll
  for (int r = 0; r < 4; ++r) {
    GLOAD_LDS16(gA[r], &Abuf[0][r * 2048 + ldsO]);
    GLOAD_LDS16(gB[r], &Bbuf[0][r * 2048 + ldsO]);
  }

  for (int t = 0; t < NT; ++t) {
    int tn = t + 1; if (tn == NT) tn = 0;          // wrap keeps vmcnt math uniform
    const long ko = (long)tn << 6;
    const int nb = (t + 1) & 1;
#pragma unroll
    for (int r = 0; r < 4; ++r) {
      GLOAD_LDS16(gA[r] + ko, &Abuf[nb][r * 2048 + ldsO]);
      GLOAD_LDS16(gB[r] + ko, &Bbuf[nb][r * 2048 + ldsO]);
    }
    // counted wait: current tile's 8 (oldest) landed; next tile's 8 stay in flight
    asm volatile("s_waitcnt vmcnt(8)" ::: "memory");
    __builtin_amdgcn_s_barrier();
    __builtin_amdgcn_sched_barrier(0);
    const unsigned short* Al = Abuf[t & 1];
    const unsigned short* Bl = Bbuf[t & 1];
#pragma unroll
    for (int kk = 0; kk < 2; ++kk) {
      bf16x8 af[4], bfr[4];
#pragma unroll
      for (int m = 0; m < 4; ++m) {
        int Pb = swz((wm * 64 + m * 16 + lr) * 128 + kk * 64 + khb);
        af[m] = *(const bf16x8*)((const char*)Al + Pb);
      }
#pragma unroll
      for (int n = 0; n < 4; ++n) {
        int Pb = swz((wn * 64 + n * 16 + lr) * 128 + kk * 64 + khb);
        bfr[n] = *(const bf16x8*)((const char*)Bl + Pb);
      }
      __builtin_amdgcn_s_setprio(1);
#pragma unroll
      for (int m = 0; m < 4; ++m)
#pragma unroll
        for (int n = 0; n < 4; ++n)
          acc[m][n] = mfma16(af[m], bfr[n], acc[m][n]);
      __builtin_amdgcn_s_setprio(0);
    }
    __builtin_amdgcn_sched_barrier(0);
    __builtin_amdgcn_s_barrier();
    __builtin_amdgcn_sched_barrier(0);
  }
  asm volatile("s_waitcnt vmcnt(0)" ::: "memory");   // drain wrapped stage
  __builtin_amdgcn_s_barrier();                      // all DMA landed before Abuf reuse

  const int rb = (lane >> 4) * 4;

  if constexpr (EPI == 7) {
#pragma unroll
    for (int m = 0; m < 4; ++m) {
      int lrow = wm * 64 + m * 16 + rb;
      long gr0 = row0 + lrow;
#pragma unroll
      for (int n = 0; n < 4; ++n) {
        long gc = col0 + wn * 64 + n * 16 + lr;
        long o = (long)z * (512L * 1024L) + gc * 1024L + gr0;
        f32x4 res = *(const f32x4*)&residual[o];
        float bb = bias[gc];
        f32x4 st;
#pragma unroll
        for (int r = 0; r < 4; ++r)
          st[r] = acc[m][n][r] * sred[lrow + r] + bb + res[r];
        *(f32x4*)&((float*)Dp)[o] = st;
      }
    }
    return;
  }

  // ---- bf16-storing epilogues (0/1/5): per-wave LDS repack -> coalesced us8 stores
  float* slab = ((float*)(void*)Abuf) + wave * 1088;     // 16 rows x 68 f32 per wave
  const int jt = by;
  unsigned short* Dst = (unsigned short*)Dp + (long)z * Dz;
#pragma unroll
  for (int m = 0; m < 4; ++m) {
    float ps[4] = {0.f, 0.f, 0.f, 0.f};
#pragma unroll
    for (int n = 0; n < 4; ++n) {
      float bcol = 0.f;
      if constexpr (EPI == 0) bcol = bias[col0 + wn * 64 + n * 16 + lr];
#pragma unroll
      for (int r = 0; r < 4; ++r) {
        float v = acc[m][n][r];
        if constexpr (EPI == 0) v += bcol;
        else if constexpr (EPI == 1) v += bias[row0 + wm * 64 + m * 16 + rb + r];
        else if constexpr (EPI == 5) { v = exp2f(v * scale); ps[r] += v; }
        slab[(rb + r) * 68 + n * 16 + lr] = v;
      }
    }
    if constexpr (EPI == 5) {
#pragma unroll
      for (int r = 0; r < 4; ++r) {
        ps[r] += __shfl_xor(ps[r], 1);
        ps[r] += __shfl_xor(ps[r], 2);
        ps[r] += __shfl_xor(ps[r], 4);
        ps[r] += __shfl_xor(ps[r], 8);
      }
      if (lr == 0) {
#pragma unroll
        for (int r = 0; r < 4; ++r)
          rs[((long)z * 1024 + row0 + wm * 64 + m * 16 + rb + r) * 16 + jt * 2 + wn] = ps[r];
      }
    }
#pragma unroll
    for (int p = 0; p < 2; ++p) {
      int rl = p * 8 + (lane >> 3);
      int c8 = (lane & 7) * 8;
      f32x4 v0 = *(const f32x4*)&slab[rl * 68 + c8];
      f32x4 v1 = *(const f32x4*)&slab[rl * 68 + c8 + 4];
      us8 o;
      o[0] = f2bf(v0.x); o[1] = f2bf(v0.y); o[2] = f2bf(v0.z); o[3] = f2bf(v0.w);
      o[4] = f2bf(v1.x); o[5] = f2bf(v1.y); o[6] = f2bf(v1.z); o[7] = f2bf(v1.w);
      *(us8*)&Dst[(row0 + wm * 64 + m * 16 + rl) * ldd + col0 + wn * 64 + c8] = o;
    }
  }
}

extern "C" void kernel_launch(void* const* d_in, const int* in_sizes, int n_in,
                              void* d_out, int out_size, void* d_ws, size_t ws_size,
                              hipStream_t stream) {
  const float* x     = (const float*)d_in[0];
  const float* gamma = (const float*)d_in[1];
  const float* beta  = (const float*)d_in[2];
  const float* wq    = (const float*)d_in[3];
  const float* bq    = (const float*)d_in[4];
  const float* wk    = (const float*)d_in[5];
  const float* bk    = (const float*)d_in[6];
  const float* wv    = (const float*)d_in[7];
  const float* bv    = (const float*)d_in[8];
  const float* wo    = (const float*)d_in[9];
  const float* bo    = (const float*)d_in[10];
  float* out = (float*)d_out;

  char* ws = (char*)d_ws;
  unsigned short* ht   = (unsigned short*)(ws + 0);           // [16384,512] bf16
  unsigned short* qkt  = (unsigned short*)(ws + 16777216);    // [16384,1024] bf16 (q | k)
  unsigned short* VWT  = (unsigned short*)(ws + 50331648);    // [512,16384] bf16 (wo.v)
  unsigned short* S    = (unsigned short*)(ws + 83886080);    // [16,1024,1024] bf16 (P unnorm)
  unsigned short* wqkb = (unsigned short*)(ws + 117440512);   // [1024,512] bf16
  unsigned short* wvT  = (unsigned short*)(ws + 119537664);   // [512,512] bf16 (k,c)
  unsigned short* wob  = (unsigned short*)(ws + 120061952);   // [512,512] bf16
  unsigned short* WVO  = (unsigned short*)(ws + 120586240);   // [512,512] bf16
  float* bqk           = (float*)(ws + 121110528);            // [1024] f32
  float* bvo           = (float*)(ws + 121114624);            // [512] f32
  float* rs            = (float*)(ws + 121122816);            // [16,1024,16] f32 partial rowsums

  prep_w<<<1090, 256, 0, stream>>>(wq, wk, wo, wv, bq, bk, bv,
                                   wqkb, wob, wvT, bqk, bvo);
  wprod<<<dim3(8, 8), 256, 0, stream>>>(wob, wvT, WVO);
  gn_fused<<<512, 256, 0, stream>>>(x, gamma, beta, ht);

  // G1: qkt[i, j] = sum_c ht[i,c] * wqk[j,c] + bqk[j]      (128x8 = 1024 blocks)
  gemm128<0, 0, 0, 0><<<dim3(128, 8, 1), 256, 0, stream>>>(ht, 512, 0, wqkb, 512, 0,
                                                           qkt, 1024, 0, bqk, 0.f, 512, nullptr, nullptr);
  // G2: VWT[o, t] = sum_k WVO[o,k] * ht[t,k] + bvo[o]      (4x128 = 512 blocks)
  gemm128<1, 0, 0, 0><<<dim3(4, 128, 1), 256, 0, stream>>>(WVO, 512, 0, ht, 512, 0,
                                                           VWT, 16384, 0, bvo, 0.f, 512, nullptr, nullptr);
  // G3: P[b,i,j] = exp2(scale' * sum_c q[i,c]*k[j,c]), rowsum partials -> rs  (8x8x16, XCD-swz)
  gemm128<5, 3, 3, 1><<<dim3(8, 8, 16), 256, 0, stream>>>(qkt, 1024, 1048576L, qkt + 512, 1024, 1048576L,
                                                          S, 1024, 1048576L, nullptr,
                                                          0.06375871416f, 512, nullptr, rs);
  // G4: out[b,o,n] = dinv_n * sum_j P[b,n,j] * VWT[o, b*N+j] + bo[o] + x[b,o,n]  (8x4x16, XCD-swz)
  gemm128<7, 3, 2, 1><<<dim3(8, 4, 16), 256, 0, stream>>>(S, 1024, 1048576L,
                                                          VWT, 16384, 1024,
                                                          out, 0, 0, bo, 0.f, 1024, x, rs);
}